// Round 18
// baseline (78.030 us; speedup 1.0000x reference)
//
#include <hip/hip_runtime.h>
#include <hip/hip_bf16.h>

#define C_DIM 512
#define S_DIM 1024
#define NH 8
#define HD 64  // head dim

typedef __attribute__((ext_vector_type(8))) short bf16x8;            // MFMA A/B frag (8 bf16)
typedef __attribute__((ext_vector_type(8))) unsigned short u16x8;
typedef __attribute__((ext_vector_type(4))) unsigned short u16x4;
typedef __attribute__((ext_vector_type(4))) float f32x4;

__device__ __forceinline__ unsigned short f2b_hw(float f) {  // fp32 -> bf16 RNE (HW cvt)
  __hip_bfloat16 h = __float2bfloat16(f);
  return __builtin_bit_cast(unsigned short, h);
}

__device__ __forceinline__ f32x4 mfma16(bf16x8 a, bf16x8 b, f32x4 c) {
  return __builtin_amdgcn_mfma_f32_16x16x32_bf16(a, b, c, 0, 0, 0);
}

__device__ __forceinline__ void gload_lds16(const unsigned short* g, unsigned short* l) {
  __builtin_amdgcn_global_load_lds(
      (const __attribute__((address_space(1))) unsigned int*)g,
      (__attribute__((address_space(3))) unsigned int*)l, 16, 0, 0);
}

// ---------------------------------------------------------------------------
// prep: blocks [0,1024): convert Wqkv (Q-rows pre-scaled by (1/8)*log2e) and
//       Wo fp32->bf16.  blocks [1024,2048): transpose x [b][c][s] fp32 ->
//       xT [b][s][c] bf16 via 64x64 LDS tile.
// ---------------------------------------------------------------------------
__global__ __launch_bounds__(256) void prep(
    const float* __restrict__ x, const float* __restrict__ Wqkv,
    const float* __restrict__ Wo,
    unsigned short* __restrict__ WqkvB, unsigned short* __restrict__ WoB,
    unsigned short* __restrict__ xT)
{
  __shared__ float T[64][65];
  const int bid = blockIdx.x;
  if (bid < 1024) {
    const int i = bid * 256 + threadIdx.x;  // handles 4 elements
    const float* src;
    unsigned short* dst;
    int off;
    float mul = 1.0f;
    if (i < 196608) {
      src = Wqkv; dst = WqkvB; off = i * 4;
      const int o = off >> 9;               // row of Wqkv
      if ((o % 192) < 64) mul = 0.18033688011112042f;  // Q rows: (1/8)*log2(e)
    } else {
      src = Wo; dst = WoB; off = (i - 196608) * 4;
    }
    const float4 v = *(const float4*)(src + off);
    const u16x4 pk = {f2b_hw(v.x * mul), f2b_hw(v.y * mul),
                      f2b_hw(v.z * mul), f2b_hw(v.w * mul)};
    *(u16x4*)(dst + off) = pk;
  } else {
    const int idx = bid - 1024;
    const int st = idx & 15, ct = (idx >> 4) & 7, b = idx >> 7;
    const int c0 = ct * 64, s0 = st * 64;
    const int tr = threadIdx.x >> 4, tc4 = (threadIdx.x & 15) * 4;
#pragma unroll
    for (int rep = 0; rep < 4; ++rep) {
      const int c = rep * 16 + tr;
      *(float4*)&T[c][tc4] =
          *(const float4*)(x + ((size_t)(b * C_DIM + c0 + c)) * S_DIM + s0 + tc4);
    }
    __syncthreads();
#pragma unroll
    for (int rep = 0; rep < 4; ++rep) {
      const int s = rep * 16 + tr;
      const u16x4 pk = {f2b_hw(T[tc4 + 0][s]), f2b_hw(T[tc4 + 1][s]),
                        f2b_hw(T[tc4 + 2][s]), f2b_hw(T[tc4 + 3][s])};
      *(u16x4*)(xT + ((size_t)(b * S_DIM + s0 + s)) * C_DIM + c0 + tc4) = pk;
    }
  }
}

// ---------------------------------------------------------------------------
// proj_qkv — 64x256 tile: grid 4x24x8 = 768 blocks = 3/CU. vs 64x128: A
// staging redundancy halves (4 st-blocks instead of 8 -> ~49MB less L2
// traffic) and per-wave output doubles (64x64, acc[4][4]) so per-output LDS
// reads halve. LDS 40KB (A[64][64] 8KB + B[256][64] 32KB). m97 2-barrier
// loop + T2 swizzle. Scatter bf16 Q/K -> [bh][s][d]; Vt -> [bh][d][s] with
// within-64 col perm p = (s&35)|((s&12)<<1)|((s&16)>>2) so attn's PV
// A-fragment is one contiguous ds_read_b128.
// ---------------------------------------------------------------------------
__global__ __launch_bounds__(256) void proj_qkv(
    const unsigned short* __restrict__ A, const unsigned short* __restrict__ Bm,
    unsigned short* __restrict__ Q, unsigned short* __restrict__ K,
    unsigned short* __restrict__ Vt)
{
  const int b = blockIdx.z, ot = blockIdx.y, st = blockIdx.x;
  const int o0 = ot * 64, s0 = st * 256;
  const int tid = threadIdx.x;
  const int w = tid >> 6, lane = tid & 63;
  const int g = lane >> 4, j16 = lane & 15;

  __shared__ __align__(16) unsigned short lds[2560 * 8];  // 40KB: A[64][64] | B[256][64]
  char* const Al = (char*)lds;
  char* const Bl = (char*)lds + 8192;

  f32x4 acc[4][4];
#pragma unroll
  for (int mt = 0; mt < 4; ++mt)
#pragma unroll
    for (int nt = 0; nt < 4; ++nt) {
      acc[mt][nt].x = 0.f; acc[mt][nt].y = 0.f;
      acc[mt][nt].z = 0.f; acc[mt][nt].w = 0.f;
    }

  for (int k0 = 0; k0 < C_DIM; k0 += 64) {
    __syncthreads();
    // A: 512 chunks (it 0..1), B: 2048 chunks (it 2..9); 10 loads/thread
#pragma unroll
    for (int it = 0; it < 10; ++it) {
      const int cid = (it < 2) ? (it * 256 + tid) : ((it - 2) * 256 + tid);
      const int row = cid >> 3;
      const int srcb = ((cid & 7) << 4) ^ ((row & 7) << 4);
      if (it < 2) {
        gload_lds16(A + (size_t)(o0 + row) * C_DIM + k0 + (srcb >> 1),
                    lds + (size_t)(it * 256 + w * 64) * 8);
      } else {
        gload_lds16(Bm + ((size_t)(b * S_DIM) + s0 + row) * C_DIM + k0 + (srcb >> 1),
                    lds + (size_t)(512 + (it - 2) * 256 + w * 64) * 8);
      }
    }
    __syncthreads();

#pragma unroll
    for (int ks = 0; ks < 2; ++ks) {
      bf16x8 af[4], bfr[4];
#pragma unroll
      for (int mt = 0; mt < 4; ++mt) {
        const int r = mt * 16 + j16;                 // o row 0..63
        af[mt] = __builtin_bit_cast(
            bf16x8, *(const u16x8*)(Al + r * 128 + ((ks * 64 + g * 16) ^ ((r & 7) << 4))));
      }
#pragma unroll
      for (int nt = 0; nt < 4; ++nt) {
        const int r = w * 64 + nt * 16 + j16;        // s row 0..255
        bfr[nt] = __builtin_bit_cast(
            bf16x8, *(const u16x8*)(Bl + r * 128 + ((ks * 64 + g * 16) ^ ((r & 7) << 4))));
      }
#pragma unroll
      for (int mt = 0; mt < 4; ++mt)
#pragma unroll
        for (int nt = 0; nt < 4; ++nt)
          acc[mt][nt] = mfma16(af[mt], bfr[nt], acc[mt][nt]);
    }
  }

  // epilogue: o = o0 + mt*16 + g*4 + q ; s = s0 + w*64 + nt*16 + j16
#pragma unroll
  for (int mt = 0; mt < 4; ++mt) {
    const int ob = o0 + mt * 16 + g * 4;
    // 16-aligned o-blocks never cross the 64/192 boundaries -> uniform per mt
    const int head = ob / 192, type = (ob % 192) >> 6, d = ob & 63;
    const int bh = b * NH + head;
    if (type < 2) {  // Q (pre-scaled via W) or K -> [bh][s][d]
      unsigned short* const dst = (type == 0) ? Q : K;
#pragma unroll
      for (int nt = 0; nt < 4; ++nt) {
        const int s = s0 + w * 64 + nt * 16 + j16;
        const f32x4 a = acc[mt][nt];
        const u16x4 pk = {f2b_hw(a.x), f2b_hw(a.y), f2b_hw(a.z), f2b_hw(a.w)};
        *(u16x4*)(dst + ((size_t)bh * S_DIM + s) * HD + d) = pk;
      }
    } else {  // V -> [bh][d][s] with permuted within-64 column order
#pragma unroll
      for (int nt = 0; nt < 4; ++nt) {
        const int spos = nt * 16 + j16;  // (w*64 aligned) position within 64-block
        const int p = (spos & 35) | ((spos & 12) << 1) | ((spos & 16) >> 2);
        const size_t col = (size_t)(s0 + w * 64) + p;
        const f32x4 a = acc[mt][nt];
#pragma unroll
        for (int q = 0; q < 4; ++q)
          Vt[((size_t)bh * HD + d + q) * S_DIM + col] = f2b_hw(a[q]);
      }
    }
  }
}

// ---------------------------------------------------------------------------
// proj_out — 64x128 tile, grid 8x8x8 = 512 blocks = 2/CU (R15 win).
// 4 waves each own 64x32 (acc[4][2]); LDS 24KB. m97 2-barrier loop + swizzle.
// y = C + bo + resid (fp32, [b][o][s]).
// ---------------------------------------------------------------------------
__global__ __launch_bounds__(256) void proj_out(
    const unsigned short* __restrict__ A, const unsigned short* __restrict__ Bm,
    float* __restrict__ y, const float* __restrict__ bo,
    const float* __restrict__ resid)
{
  const int b = blockIdx.z, ot = blockIdx.y, st = blockIdx.x;
  const int o0 = ot * 64, s0 = st * 128;
  const int tid = threadIdx.x;
  const int w = tid >> 6, lane = tid & 63;
  const int g = lane >> 4, j16 = lane & 15;

  __shared__ __align__(16) unsigned short lds[1536 * 8];  // 24KB: A[64][64] | B[128][64]
  char* const Al = (char*)lds;
  char* const Bl = (char*)lds + 8192;

  f32x4 acc[4][2];
#pragma unroll
  for (int mt = 0; mt < 4; ++mt)
#pragma unroll
    for (int nt = 0; nt < 2; ++nt) {
      acc[mt][nt].x = 0.f; acc[mt][nt].y = 0.f;
      acc[mt][nt].z = 0.f; acc[mt][nt].w = 0.f;
    }

  for (int k0 = 0; k0 < C_DIM; k0 += 64) {
    __syncthreads();
#pragma unroll
    for (int it = 0; it < 6; ++it) {
      const int cid = (it < 2) ? (it * 256 + tid) : ((it - 2) * 256 + tid);
      const int row = cid >> 3;
      const int srcb = ((cid & 7) << 4) ^ ((row & 7) << 4);
      if (it < 2) {
        gload_lds16(A + (size_t)(o0 + row) * C_DIM + k0 + (srcb >> 1),
                    lds + (size_t)(it * 256 + w * 64) * 8);
      } else {
        gload_lds16(Bm + ((size_t)(b * S_DIM) + s0 + row) * C_DIM + k0 + (srcb >> 1),
                    lds + (size_t)(512 + (it - 2) * 256 + w * 64) * 8);
      }
    }
    __syncthreads();

#pragma unroll
    for (int ks = 0; ks < 2; ++ks) {
      bf16x8 af[4], bfr[2];
#pragma unroll
      for (int mt = 0; mt < 4; ++mt) {
        const int r = mt * 16 + j16;                 // o row 0..63
        af[mt] = __builtin_bit_cast(
            bf16x8, *(const u16x8*)(Al + r * 128 + ((ks * 64 + g * 16) ^ ((r & 7) << 4))));
      }
#pragma unroll
      for (int nt = 0; nt < 2; ++nt) {
        const int r = w * 32 + nt * 16 + j16;        // s row 0..127
        bfr[nt] = __builtin_bit_cast(
            bf16x8, *(const u16x8*)(Bl + r * 128 + ((ks * 64 + g * 16) ^ ((r & 7) << 4))));
      }
#pragma unroll
      for (int mt = 0; mt < 4; ++mt)
#pragma unroll
        for (int nt = 0; nt < 2; ++nt)
          acc[mt][nt] = mfma16(af[mt], bfr[nt], acc[mt][nt]);
    }
  }

#pragma unroll
  for (int mt = 0; mt < 4; ++mt) {
    const int ob = o0 + mt * 16 + g * 4;
#pragma unroll
    for (int nt = 0; nt < 2; ++nt) {
      const int s = s0 + w * 32 + nt * 16 + j16;
#pragma unroll
      for (int q = 0; q < 4; ++q) {
        const int o = ob + q;
        const size_t idx = ((size_t)(b * C_DIM + o)) * S_DIM + s;
        y[idx] = acc[mt][nt][q] + bo[o] + resid[idx];
      }
    }
  }
}

// ---------------------------------------------------------------------------
// MFMA flash attention — R11 exact (best measured). QBLK=128, 8 waves
// (512 thr), each wave 16 q-rows; 3-buffer counted-vmcnt ring:
//   tile kt: vmcnt(2) [kt's 2 loads done, kt+1's in flight] -> s_barrier ->
//            STAGE(kt+2) -> QK^T -> exp2/pack (P in registers) -> PV
// P fully in registers (PV k-slot map key = ks*32+(idx>>2)*16+g*4+(idx&3);
// Vt global layout pre-permuted so V A-frag is one ds_read_b128).
// Normalization (1/l) in the epilogue (l is per (head,q) — R5 lesson).
// Grid (bh, qb): blocks sharing a head's K/V are id-strided by 64 -> same XCD.
// FROZEN: R9/R16 (T15: spill / neutral), R10 (QBLK=64), R12 (QBLK=256),
// R13/R14 (KVBLK=128) all failed to beat this.
// ---------------------------------------------------------------------------
__global__ __launch_bounds__(512) void attn_mfma(
    const unsigned short* __restrict__ Qg, const unsigned short* __restrict__ Kg,
    const unsigned short* __restrict__ Vg, unsigned short* __restrict__ AOt)
{
  const int bh = blockIdx.x;   // 0..63 (fast dim -> same-XCD KV sharing)
  const int qb = blockIdx.y;   // 0..7
  const int b = bh >> 3, head = bh & 7;
  const int tid = threadIdx.x;
  const int w = tid >> 6, lane = tid & 63;   // 8 waves
  const int g = lane >> 4, j16 = lane & 15;
  const int qw0 = qb * 128 + w * 16;  // this wave's 16 q-rows

  __shared__ __align__(16) unsigned short KV[3][2][4096];  // 48KB ring: [buf][K/V][64x64]

  // Q B-fragment resident in registers: j=q=lane&15, k-slot (g,reg)->d
  bf16x8 qf[2];
#pragma unroll
  for (int ks = 0; ks < 2; ++ks)
    qf[ks] = __builtin_bit_cast(
        bf16x8, *(const u16x8*)(Qg + ((size_t)bh * S_DIM + qw0 + j16) * HD +
                                ks * 32 + g * 8));

  // staging: 512 x 16B chunks per tensor over 512 threads = 1 chunk each
  // per tensor (2 loads/thread). dst is wave-uniform; lane offset automatic.
  auto STAGE = [&](int buf, int k0) {
    const int cid = tid;                      // w*64 + lane
    const int row = cid >> 3;
    const int srcb = ((cid & 7) << 4) ^ ((row & 7) << 4);  // inverse swizzle on src
    unsigned short* const dst = &KV[buf][0][0] + (size_t)(w * 64) * 8;
    gload_lds16(Kg + ((size_t)bh * S_DIM + k0 + row) * HD + (srcb >> 1), dst);
    gload_lds16(Vg + ((size_t)bh * HD + row) * S_DIM + k0 + (srcb >> 1), dst + 4096);
  };

  f32x4 oacc[4];
#pragma unroll
  for (int mt = 0; mt < 4; ++mt) {
    oacc[mt].x = 0.f; oacc[mt].y = 0.f; oacc[mt].z = 0.f; oacc[mt].w = 0.f;
  }
  float lsum = 0.f;

  STAGE(0, 0);
  STAGE(1, 64);

  for (int kt = 0; kt < 16; ++kt) {
    // wait for THIS tile's 2 loads (oldest); keep next tile's 2 in flight
    if (kt < 15) asm volatile("s_waitcnt vmcnt(2)" ::: "memory");
    else         asm volatile("s_waitcnt vmcnt(0)" ::: "memory");
    __builtin_amdgcn_s_barrier();  // all waves' kt loads visible; slot (kt+2)%3
                                   // was last read in tile kt-1 -> reusable
    if (kt < 14) STAGE((kt + 2) % 3, (kt + 2) * 64);

    const char* const Kl = (const char*)KV + (kt % 3) * 16384;
    const char* const Vl = Kl + 8192;

    // ---- S^T = K · Q^T  (key = mt*16+g*4+reg, q = j16)
    f32x4 sacc[4];
    __builtin_amdgcn_s_setprio(1);
#pragma unroll
    for (int mt = 0; mt < 4; ++mt) {
      const int row = mt * 16 + j16;
      const int sw = (row & 7) << 4;
      const bf16x8 kf0 = __builtin_bit_cast(
          bf16x8, *(const u16x8*)(Kl + row * 128 + ((g * 16) ^ sw)));
      f32x4 z; z.x = 0.f; z.y = 0.f; z.z = 0.f; z.w = 0.f;
      sacc[mt] = mfma16(kf0, qf[0], z);
      const bf16x8 kf1 = __builtin_bit_cast(
          bf16x8, *(const u16x8*)(Kl + row * 128 + ((64 + g * 16) ^ sw)));
      sacc[mt] = mfma16(kf1, qf[1], sacc[mt]);
    }
    __builtin_amdgcn_s_setprio(0);

    // ---- exp2 + pack P in registers: pf4[mt] = bf16 of p[reg 0..3]
    u16x4 pf4[4];
#pragma unroll
    for (int mt = 0; mt < 4; ++mt) {
      f32x4 p;
      p.x = exp2f(sacc[mt].x);
      p.y = exp2f(sacc[mt].y);
      p.z = exp2f(sacc[mt].z);
      p.w = exp2f(sacc[mt].w);
      lsum += (p.x + p.y) + (p.z + p.w);
      pf4[mt] = u16x4{f2b_hw(p.x), f2b_hw(p.y), f2b_hw(p.z), f2b_hw(p.w)};
    }

    // ---- O^T += V^T · P^T   (k-slot map: key = ks*32 + (idx>>2)*16 + g*4 + (idx&3))
    __builtin_amdgcn_s_setprio(1);
#pragma unroll
    for (int ks = 0; ks < 2; ++ks) {
      const bf16x8 pfr = __builtin_bit_cast(
          bf16x8, __builtin_shufflevector(pf4[2 * ks], pf4[2 * ks + 1],
                                          0, 1, 2, 3, 4, 5, 6, 7));
#pragma unroll
      for (int mt = 0; mt < 4; ++mt) {
        const int row = mt * 16 + j16;
        const int sw = (row & 7) << 4;
        const bf16x8 vf = __builtin_bit_cast(
            bf16x8, *(const u16x8*)(Vl + row * 128 + ((ks * 64 + g * 16) ^ sw)));
        oacc[mt] = mfma16(vf, pfr, oacc[mt]);
      }
    }
    __builtin_amdgcn_s_setprio(0);
  }

  // softmax denominator: q col = lane&15; reduce across the 4 lane-groups
  lsum += __shfl_xor(lsum, 16);
  lsum += __shfl_xor(lsum, 32);
  const float rl = 1.f / lsum;

  // write NORMALIZED AO^T [b][s][c] bf16, c = head*64 + d; d = mt*16+g*4+r
  const int q = qw0 + j16;
#pragma unroll
  for (int mt = 0; mt < 4; ++mt) {
    const f32x4 a = oacc[mt];
    const u16x4 pk = {f2b_hw(a.x * rl), f2b_hw(a.y * rl), f2b_hw(a.z * rl), f2b_hw(a.w * rl)};
    *(u16x4*)(AOt + ((size_t)(b * S_DIM + q)) * C_DIM + head * HD + mt * 16 + g * 4) = pk;
  }
}

extern "C" void kernel_launch(void* const* d_in, const int* in_sizes, int n_in,
                              void* d_out, int out_size, void* d_ws, size_t ws_size,
                              hipStream_t stream) {
  const float* x    = (const float*)d_in[0];
  const float* Wqkv = (const float*)d_in[1];
  const float* Wo   = (const float*)d_in[2];
  const float* bo   = (const float*)d_in[3];
  float* y = (float*)d_out;

  unsigned short* WqkvB = (unsigned short*)d_ws;           // 786432
  unsigned short* WoB   = WqkvB + 786432;                  // 262144
  unsigned short* xT    = WoB + 262144;                    // 4194304
  unsigned short* Q     = xT + 4194304;                    // 4194304
  unsigned short* K     = Q + 4194304;
  unsigned short* Vt    = K + 4194304;
  unsigned short* AOt   = Vt + 4194304;                    // 4194304

  prep<<<dim3(2048), 256, 0, stream>>>(x, Wqkv, Wo, WqkvB, WoB, xT);
  proj_qkv<<<dim3(4, 24, 8), 256, 0, stream>>>(WqkvB, xT, Q, K, Vt);
  attn_mfma<<<dim3(64, 8), 512, 0, stream>>>(Q, K, Vt, AOt);
  proj_out<<<dim3(8, 8, 8), 256, 0, stream>>>(WoB, AOt, y, bo, x);
}

// Round 19
// 75.616 us; speedup vs baseline: 1.0319x; 1.0319x over previous
//
#include <hip/hip_runtime.h>
#include <hip/hip_bf16.h>

#define C_DIM 512
#define S_DIM 1024
#define NH 8
#define HD 64  // head dim

typedef __attribute__((ext_vector_type(8))) short bf16x8;            // MFMA A/B frag (8 bf16)
typedef __attribute__((ext_vector_type(8))) unsigned short u16x8;
typedef __attribute__((ext_vector_type(4))) unsigned short u16x4;
typedef __attribute__((ext_vector_type(4))) float f32x4;

__device__ __forceinline__ unsigned short f2b_hw(float f) {  // fp32 -> bf16 RNE (HW cvt)
  __hip_bfloat16 h = __float2bfloat16(f);
  return __builtin_bit_cast(unsigned short, h);
}

__device__ __forceinline__ f32x4 mfma16(bf16x8 a, bf16x8 b, f32x4 c) {
  return __builtin_amdgcn_mfma_f32_16x16x32_bf16(a, b, c, 0, 0, 0);
}

__device__ __forceinline__ void gload_lds16(const unsigned short* g, unsigned short* l) {
  __builtin_amdgcn_global_load_lds(
      (const __attribute__((address_space(1))) unsigned int*)g,
      (__attribute__((address_space(3))) unsigned int*)l, 16, 0, 0);
}

// ---------------------------------------------------------------------------
// prep: blocks [0,1024): convert Wqkv (Q-rows pre-scaled by (1/8)*log2e) and
//       Wo fp32->bf16.  blocks [1024,2048): transpose x [b][c][s] fp32 ->
//       xT [b][s][c] bf16 via 64x64 LDS tile.
// ---------------------------------------------------------------------------
__global__ __launch_bounds__(256) void prep(
    const float* __restrict__ x, const float* __restrict__ Wqkv,
    const float* __restrict__ Wo,
    unsigned short* __restrict__ WqkvB, unsigned short* __restrict__ WoB,
    unsigned short* __restrict__ xT)
{
  __shared__ float T[64][65];
  const int bid = blockIdx.x;
  if (bid < 1024) {
    const int i = bid * 256 + threadIdx.x;  // handles 4 elements
    const float* src;
    unsigned short* dst;
    int off;
    float mul = 1.0f;
    if (i < 196608) {
      src = Wqkv; dst = WqkvB; off = i * 4;
      const int o = off >> 9;               // row of Wqkv
      if ((o % 192) < 64) mul = 0.18033688011112042f;  // Q rows: (1/8)*log2(e)
    } else {
      src = Wo; dst = WoB; off = (i - 196608) * 4;
    }
    const float4 v = *(const float4*)(src + off);
    const u16x4 pk = {f2b_hw(v.x * mul), f2b_hw(v.y * mul),
                      f2b_hw(v.z * mul), f2b_hw(v.w * mul)};
    *(u16x4*)(dst + off) = pk;
  } else {
    const int idx = bid - 1024;
    const int st = idx & 15, ct = (idx >> 4) & 7, b = idx >> 7;
    const int c0 = ct * 64, s0 = st * 64;
    const int tr = threadIdx.x >> 4, tc4 = (threadIdx.x & 15) * 4;
#pragma unroll
    for (int rep = 0; rep < 4; ++rep) {
      const int c = rep * 16 + tr;
      *(float4*)&T[c][tc4] =
          *(const float4*)(x + ((size_t)(b * C_DIM + c0 + c)) * S_DIM + s0 + tc4);
    }
    __syncthreads();
#pragma unroll
    for (int rep = 0; rep < 4; ++rep) {
      const int s = rep * 16 + tr;
      const u16x4 pk = {f2b_hw(T[tc4 + 0][s]), f2b_hw(T[tc4 + 1][s]),
                        f2b_hw(T[tc4 + 2][s]), f2b_hw(T[tc4 + 3][s])};
      *(u16x4*)(xT + ((size_t)(b * S_DIM + s0 + s)) * C_DIM + c0 + tc4) = pk;
    }
  }
}

// ---------------------------------------------------------------------------
// proj_qkv — 64x128 tile (R17 geometry, measured best: grid 8x24x8 = 1536
// blocks = 6/CU; R18's 64x256 @ 3/CU regressed — blocks/CU dominates staging
// bytes for these small-K GEMMs). 4 waves each own 64x32 (acc[4][2], ~70
// VGPR); LDS 24KB. m97 2-barrier loop + T2 swizzle. Scatter bf16 Q/K ->
// [bh][s][d]; Vt -> [bh][d][s] with within-64 col perm
// p = (s&35)|((s&12)<<1)|((s&16)>>2) so attn's PV A-frag is one ds_read_b128.
// ---------------------------------------------------------------------------
__global__ __launch_bounds__(256) void proj_qkv(
    const unsigned short* __restrict__ A, const unsigned short* __restrict__ Bm,
    unsigned short* __restrict__ Q, unsigned short* __restrict__ K,
    unsigned short* __restrict__ Vt)
{
  const int b = blockIdx.z, ot = blockIdx.y, st = blockIdx.x;
  const int o0 = ot * 64, s0 = st * 128;
  const int tid = threadIdx.x;
  const int w = tid >> 6, lane = tid & 63;
  const int g = lane >> 4, j16 = lane & 15;

  __shared__ __align__(16) unsigned short lds[1536 * 8];  // 24KB: A[64][64] | B[128][64]
  char* const Al = (char*)lds;
  char* const Bl = (char*)lds + 8192;

  f32x4 acc[4][2];
#pragma unroll
  for (int mt = 0; mt < 4; ++mt)
#pragma unroll
    for (int nt = 0; nt < 2; ++nt) {
      acc[mt][nt].x = 0.f; acc[mt][nt].y = 0.f;
      acc[mt][nt].z = 0.f; acc[mt][nt].w = 0.f;
    }

  for (int k0 = 0; k0 < C_DIM; k0 += 64) {
    __syncthreads();
    // A: 512 chunks (it 0..1), B: 1024 chunks (it 2..5); 6 loads/thread
#pragma unroll
    for (int it = 0; it < 6; ++it) {
      const int cid = (it < 2) ? (it * 256 + tid) : ((it - 2) * 256 + tid);
      const int row = cid >> 3;
      const int srcb = ((cid & 7) << 4) ^ ((row & 7) << 4);
      if (it < 2) {
        gload_lds16(A + (size_t)(o0 + row) * C_DIM + k0 + (srcb >> 1),
                    lds + (size_t)(it * 256 + w * 64) * 8);
      } else {
        gload_lds16(Bm + ((size_t)(b * S_DIM) + s0 + row) * C_DIM + k0 + (srcb >> 1),
                    lds + (size_t)(512 + (it - 2) * 256 + w * 64) * 8);
      }
    }
    __syncthreads();

#pragma unroll
    for (int ks = 0; ks < 2; ++ks) {
      bf16x8 af[4], bfr[2];
#pragma unroll
      for (int mt = 0; mt < 4; ++mt) {
        const int r = mt * 16 + j16;                 // o row 0..63
        af[mt] = __builtin_bit_cast(
            bf16x8, *(const u16x8*)(Al + r * 128 + ((ks * 64 + g * 16) ^ ((r & 7) << 4))));
      }
#pragma unroll
      for (int nt = 0; nt < 2; ++nt) {
        const int r = w * 32 + nt * 16 + j16;        // s row 0..127
        bfr[nt] = __builtin_bit_cast(
            bf16x8, *(const u16x8*)(Bl + r * 128 + ((ks * 64 + g * 16) ^ ((r & 7) << 4))));
      }
#pragma unroll
      for (int mt = 0; mt < 4; ++mt)
#pragma unroll
        for (int nt = 0; nt < 2; ++nt)
          acc[mt][nt] = mfma16(af[mt], bfr[nt], acc[mt][nt]);
    }
  }

  // epilogue: o = o0 + mt*16 + g*4 + q ; s = s0 + w*32 + nt*16 + j16
#pragma unroll
  for (int mt = 0; mt < 4; ++mt) {
    const int ob = o0 + mt * 16 + g * 4;
    // 16-aligned o-blocks never cross the 64/192 boundaries -> uniform per mt
    const int head = ob / 192, type = (ob % 192) >> 6, d = ob & 63;
    const int bh = b * NH + head;
    if (type < 2) {  // Q (pre-scaled via W) or K -> [bh][s][d]
      unsigned short* const dst = (type == 0) ? Q : K;
#pragma unroll
      for (int nt = 0; nt < 2; ++nt) {
        const int s = s0 + w * 32 + nt * 16 + j16;
        const f32x4 a = acc[mt][nt];
        const u16x4 pk = {f2b_hw(a.x), f2b_hw(a.y), f2b_hw(a.z), f2b_hw(a.w)};
        *(u16x4*)(dst + ((size_t)bh * S_DIM + s) * HD + d) = pk;
      }
    } else {  // V -> [bh][d][s] with permuted within-64 column order
#pragma unroll
      for (int nt = 0; nt < 2; ++nt) {
        const int spos = (w * 32 + nt * 16 + j16) & 63;  // position within 64-block
        const int p = (spos & 35) | ((spos & 12) << 1) | ((spos & 16) >> 2);
        const size_t col = (size_t)((s0 + w * 32 + nt * 16 + j16) & ~63) + p;
        const f32x4 a = acc[mt][nt];
#pragma unroll
        for (int q = 0; q < 4; ++q)
          Vt[((size_t)bh * HD + d + q) * S_DIM + col] = f2b_hw(a[q]);
      }
    }
  }
}

// ---------------------------------------------------------------------------
// proj_out — 64x128 tile, grid 8x8x8 = 512 blocks = 2/CU (R15 win).
// 4 waves each own 64x32 (acc[4][2]); LDS 24KB. m97 2-barrier loop + swizzle.
// y = C + bo + resid (fp32, [b][o][s]).
// ---------------------------------------------------------------------------
__global__ __launch_bounds__(256) void proj_out(
    const unsigned short* __restrict__ A, const unsigned short* __restrict__ Bm,
    float* __restrict__ y, const float* __restrict__ bo,
    const float* __restrict__ resid)
{
  const int b = blockIdx.z, ot = blockIdx.y, st = blockIdx.x;
  const int o0 = ot * 64, s0 = st * 128;
  const int tid = threadIdx.x;
  const int w = tid >> 6, lane = tid & 63;
  const int g = lane >> 4, j16 = lane & 15;

  __shared__ __align__(16) unsigned short lds[1536 * 8];  // 24KB: A[64][64] | B[128][64]
  char* const Al = (char*)lds;
  char* const Bl = (char*)lds + 8192;

  f32x4 acc[4][2];
#pragma unroll
  for (int mt = 0; mt < 4; ++mt)
#pragma unroll
    for (int nt = 0; nt < 2; ++nt) {
      acc[mt][nt].x = 0.f; acc[mt][nt].y = 0.f;
      acc[mt][nt].z = 0.f; acc[mt][nt].w = 0.f;
    }

  for (int k0 = 0; k0 < C_DIM; k0 += 64) {
    __syncthreads();
#pragma unroll
    for (int it = 0; it < 6; ++it) {
      const int cid = (it < 2) ? (it * 256 + tid) : ((it - 2) * 256 + tid);
      const int row = cid >> 3;
      const int srcb = ((cid & 7) << 4) ^ ((row & 7) << 4);
      if (it < 2) {
        gload_lds16(A + (size_t)(o0 + row) * C_DIM + k0 + (srcb >> 1),
                    lds + (size_t)(it * 256 + w * 64) * 8);
      } else {
        gload_lds16(Bm + ((size_t)(b * S_DIM) + s0 + row) * C_DIM + k0 + (srcb >> 1),
                    lds + (size_t)(512 + (it - 2) * 256 + w * 64) * 8);
      }
    }
    __syncthreads();

#pragma unroll
    for (int ks = 0; ks < 2; ++ks) {
      bf16x8 af[4], bfr[2];
#pragma unroll
      for (int mt = 0; mt < 4; ++mt) {
        const int r = mt * 16 + j16;                 // o row 0..63
        af[mt] = __builtin_bit_cast(
            bf16x8, *(const u16x8*)(Al + r * 128 + ((ks * 64 + g * 16) ^ ((r & 7) << 4))));
      }
#pragma unroll
      for (int nt = 0; nt < 2; ++nt) {
        const int r = w * 32 + nt * 16 + j16;        // s row 0..127
        bfr[nt] = __builtin_bit_cast(
            bf16x8, *(const u16x8*)(Bl + r * 128 + ((ks * 64 + g * 16) ^ ((r & 7) << 4))));
      }
#pragma unroll
      for (int mt = 0; mt < 4; ++mt)
#pragma unroll
        for (int nt = 0; nt < 2; ++nt)
          acc[mt][nt] = mfma16(af[mt], bfr[nt], acc[mt][nt]);
    }
  }

#pragma unroll
  for (int mt = 0; mt < 4; ++mt) {
    const int ob = o0 + mt * 16 + g * 4;
#pragma unroll
    for (int nt = 0; nt < 2; ++nt) {
      const int s = s0 + w * 32 + nt * 16 + j16;
#pragma unroll
      for (int q = 0; q < 4; ++q) {
        const int o = ob + q;
        const size_t idx = ((size_t)(b * C_DIM + o)) * S_DIM + s;
        y[idx] = acc[mt][nt][q] + bo[o] + resid[idx];
      }
    }
  }
}

// ---------------------------------------------------------------------------
// MFMA flash attention — R11 exact (best measured). QBLK=128, 8 waves
// (512 thr), each wave 16 q-rows; 3-buffer counted-vmcnt ring:
//   tile kt: vmcnt(2) [kt's 2 loads done, kt+1's in flight] -> s_barrier ->
//            STAGE(kt+2) -> QK^T -> exp2/pack (P in registers) -> PV
// P fully in registers (PV k-slot map key = ks*32+(idx>>2)*16+g*4+(idx&3);
// Vt global layout pre-permuted so V A-frag is one ds_read_b128).
// Normalization (1/l) in the epilogue (l is per (head,q) — R5 lesson).
// Grid (bh, qb): blocks sharing a head's K/V are id-strided by 64 -> same XCD.
// FROZEN: R9/R16 (T15: spill / neutral), R10 (QBLK=64), R12 (QBLK=256),
// R13/R14 (KVBLK=128) all failed to beat this.
// ---------------------------------------------------------------------------
__global__ __launch_bounds__(512) void attn_mfma(
    const unsigned short* __restrict__ Qg, const unsigned short* __restrict__ Kg,
    const unsigned short* __restrict__ Vg, unsigned short* __restrict__ AOt)
{
  const int bh = blockIdx.x;   // 0..63 (fast dim -> same-XCD KV sharing)
  const int qb = blockIdx.y;   // 0..7
  const int b = bh >> 3, head = bh & 7;
  const int tid = threadIdx.x;
  const int w = tid >> 6, lane = tid & 63;   // 8 waves
  const int g = lane >> 4, j16 = lane & 15;
  const int qw0 = qb * 128 + w * 16;  // this wave's 16 q-rows

  __shared__ __align__(16) unsigned short KV[3][2][4096];  // 48KB ring: [buf][K/V][64x64]

  // Q B-fragment resident in registers: j=q=lane&15, k-slot (g,reg)->d
  bf16x8 qf[2];
#pragma unroll
  for (int ks = 0; ks < 2; ++ks)
    qf[ks] = __builtin_bit_cast(
        bf16x8, *(const u16x8*)(Qg + ((size_t)bh * S_DIM + qw0 + j16) * HD +
                                ks * 32 + g * 8));

  // staging: 512 x 16B chunks per tensor over 512 threads = 1 chunk each
  // per tensor (2 loads/thread). dst is wave-uniform; lane offset automatic.
  auto STAGE = [&](int buf, int k0) {
    const int cid = tid;                      // w*64 + lane
    const int row = cid >> 3;
    const int srcb = ((cid & 7) << 4) ^ ((row & 7) << 4);  // inverse swizzle on src
    unsigned short* const dst = &KV[buf][0][0] + (size_t)(w * 64) * 8;
    gload_lds16(Kg + ((size_t)bh * S_DIM + k0 + row) * HD + (srcb >> 1), dst);
    gload_lds16(Vg + ((size_t)bh * HD + row) * S_DIM + k0 + (srcb >> 1), dst + 4096);
  };

  f32x4 oacc[4];
#pragma unroll
  for (int mt = 0; mt < 4; ++mt) {
    oacc[mt].x = 0.f; oacc[mt].y = 0.f; oacc[mt].z = 0.f; oacc[mt].w = 0.f;
  }
  float lsum = 0.f;

  STAGE(0, 0);
  STAGE(1, 64);

  for (int kt = 0; kt < 16; ++kt) {
    // wait for THIS tile's 2 loads (oldest); keep next tile's 2 in flight
    if (kt < 15) asm volatile("s_waitcnt vmcnt(2)" ::: "memory");
    else         asm volatile("s_waitcnt vmcnt(0)" ::: "memory");
    __builtin_amdgcn_s_barrier();  // all waves' kt loads visible; slot (kt+2)%3
                                   // was last read in tile kt-1 -> reusable
    if (kt < 14) STAGE((kt + 2) % 3, (kt + 2) * 64);

    const char* const Kl = (const char*)KV + (kt % 3) * 16384;
    const char* const Vl = Kl + 8192;

    // ---- S^T = K · Q^T  (key = mt*16+g*4+reg, q = j16)
    f32x4 sacc[4];
    __builtin_amdgcn_s_setprio(1);
#pragma unroll
    for (int mt = 0; mt < 4; ++mt) {
      const int row = mt * 16 + j16;
      const int sw = (row & 7) << 4;
      const bf16x8 kf0 = __builtin_bit_cast(
          bf16x8, *(const u16x8*)(Kl + row * 128 + ((g * 16) ^ sw)));
      f32x4 z; z.x = 0.f; z.y = 0.f; z.z = 0.f; z.w = 0.f;
      sacc[mt] = mfma16(kf0, qf[0], z);
      const bf16x8 kf1 = __builtin_bit_cast(
          bf16x8, *(const u16x8*)(Kl + row * 128 + ((64 + g * 16) ^ sw)));
      sacc[mt] = mfma16(kf1, qf[1], sacc[mt]);
    }
    __builtin_amdgcn_s_setprio(0);

    // ---- exp2 + pack P in registers: pf4[mt] = bf16 of p[reg 0..3]
    u16x4 pf4[4];
#pragma unroll
    for (int mt = 0; mt < 4; ++mt) {
      f32x4 p;
      p.x = exp2f(sacc[mt].x);
      p.y = exp2f(sacc[mt].y);
      p.z = exp2f(sacc[mt].z);
      p.w = exp2f(sacc[mt].w);
      lsum += (p.x + p.y) + (p.z + p.w);
      pf4[mt] = u16x4{f2b_hw(p.x), f2b_hw(p.y), f2b_hw(p.z), f2b_hw(p.w)};
    }

    // ---- O^T += V^T · P^T   (k-slot map: key = ks*32 + (idx>>2)*16 + g*4 + (idx&3))
    __builtin_amdgcn_s_setprio(1);
#pragma unroll
    for (int ks = 0; ks < 2; ++ks) {
      const bf16x8 pfr = __builtin_bit_cast(
          bf16x8, __builtin_shufflevector(pf4[2 * ks], pf4[2 * ks + 1],
                                          0, 1, 2, 3, 4, 5, 6, 7));
#pragma unroll
      for (int mt = 0; mt < 4; ++mt) {
        const int row = mt * 16 + j16;
        const int sw = (row & 7) << 4;
        const bf16x8 vf = __builtin_bit_cast(
            bf16x8, *(const u16x8*)(Vl + row * 128 + ((ks * 64 + g * 16) ^ sw)));
        oacc[mt] = mfma16(vf, pfr, oacc[mt]);
      }
    }
    __builtin_amdgcn_s_setprio(0);
  }

  // softmax denominator: q col = lane&15; reduce across the 4 lane-groups
  lsum += __shfl_xor(lsum, 16);
  lsum += __shfl_xor(lsum, 32);
  const float rl = 1.f / lsum;

  // write NORMALIZED AO^T [b][s][c] bf16, c = head*64 + d; d = mt*16+g*4+r
  const int q = qw0 + j16;
#pragma unroll
  for (int mt = 0; mt < 4; ++mt) {
    const f32x4 a = oacc[mt];
    const u16x4 pk = {f2b_hw(a.x * rl), f2b_hw(a.y * rl), f2b_hw(a.z * rl), f2b_hw(a.w * rl)};
    *(u16x4*)(AOt + ((size_t)(b * S_DIM + q)) * C_DIM + head * HD + mt * 16 + g * 4) = pk;
  }
}

extern "C" void kernel_launch(void* const* d_in, const int* in_sizes, int n_in,
                              void* d_out, int out_size, void* d_ws, size_t ws_size,
                              hipStream_t stream) {
  const float* x    = (const float*)d_in[0];
  const float* Wqkv = (const float*)d_in[1];
  const float* Wo   = (const float*)d_in[2];
  const float* bo   = (const float*)d_in[3];
  float* y = (float*)d_out;

  unsigned short* WqkvB = (unsigned short*)d_ws;           // 786432
  unsigned short* WoB   = WqkvB + 786432;                  // 262144
  unsigned short* xT    = WoB + 262144;                    // 4194304
  unsigned short* Q     = xT + 4194304;                    // 4194304
  unsigned short* K     = Q + 4194304;
  unsigned short* Vt    = K + 4194304;
  unsigned short* AOt   = Vt + 4194304;                    // 4194304

  prep<<<dim3(2048), 256, 0, stream>>>(x, Wqkv, Wo, WqkvB, WoB, xT);
  proj_qkv<<<dim3(8, 24, 8), 256, 0, stream>>>(WqkvB, xT, Q, K, Vt);
  attn_mfma<<<dim3(64, 8), 512, 0, stream>>>(Q, K, Vt, AOt);
  proj_out<<<dim3(8, 8, 8), 256, 0, stream>>>(WoB, AOt, y, bo, x);
}